// Round 2
// baseline (265.669 us; speedup 1.0000x reference)
//
#include <hip/hip_runtime.h>
#include <math.h>

// Problem constants (fixed by the reference)
#define NB 8
#define NC 9               // channels (== NUM_CLASSES)
#define PIXELS (768*768)   // 589824 pixels per batch image
#define BLOCK 256
#define PPT 8                          // pixels per thread (2 x int4), register-lean
#define CHUNK_PX (BLOCK * PPT)         // 2048
#define NCHUNK (PIXELS / CHUNK_PX)     // 288 exactly
#define NWAVE (BLOCK / 64)
#define GRID (NB * NCHUNK)             // 2304 blocks = 9 per CU
#define SLOT 80                        // per-block partial: 72 sums + 8 counts

// split-butterfly wave reduction: 8 class-sums partitioned across lanes.
// On return, lanes 0..7 hold the wave total for class cls = (p<<2)|(q<<1)|r.
__device__ __forceinline__ float butterfly8(const float s[8], int p, int q, int r)
{
    float u[4];
    #pragma unroll
    for (int j = 0; j < 4; ++j) {
        float x = p ? s[j] : s[j + 4];
        float y = __shfl_xor(x, 1, 64);
        u[j] = (p ? s[j + 4] : s[j]) + y;
    }
    float v2[2];
    #pragma unroll
    for (int j = 0; j < 2; ++j) {
        float x = q ? u[j] : u[j + 2];
        float y = __shfl_xor(x, 2, 64);
        v2[j] = (q ? u[j + 2] : u[j]) + y;
    }
    float w;
    {
        float x = r ? v2[0] : v2[1];
        float y = __shfl_xor(x, 4, 64);
        w = (r ? v2[1] : v2[0]) + y;
    }
    w += __shfl_xor(w, 8, 64);
    w += __shfl_xor(w, 16, 64);
    w += __shfl_xor(w, 32, 64);
    return w;
}

// Register-lean variant: <=64 VGPR target -> 8 waves/SIMD (32 waves/CU).
// VALU formulation proved irrelevant (rounds 0/1 identical); bet on TLP.
__global__ __launch_bounds__(BLOCK, 8)
void accum_kernel(const int* __restrict__ masks,
                  const float* __restrict__ outputs,
                  float* __restrict__ partial)   // [GRID][SLOT]
{
    int blk = blockIdx.x;
    int chunk = blk % NCHUNK;
    int b = blk / NCHUNK;
    int t = threadIdx.x;
    int wave = t >> 6;
    int lane = t & 63;

    // ---- load mask chunk ONCE (8 VGPRs) ----
    const int4* __restrict__ m4 =
        (const int4*)(masks + (size_t)b * PIXELS + (size_t)chunk * CHUNK_PX);
    int4 m0 = m4[t];
    int4 m1 = m4[t + BLOCK];

    __shared__ float red[NC][NWAVE][8];   // per-channel per-wave class sums
    __shared__ float red_c[NWAVE][8];     // per-wave class counts

    const int p = lane & 1;
    const int q = (lane >> 1) & 1;
    const int r = (lane >> 2) & 1;

    // ---- counts via ballot: accumulators live in SGPRs (wave-uniform) ----
    {
        int cnt[8];
        #pragma unroll
        for (int k = 0; k < 8; ++k) cnt[k] = 0;
        #pragma unroll
        for (int k = 1; k <= 8; ++k) {
            cnt[k - 1] += __popcll(__ballot(m0.x == k));
            cnt[k - 1] += __popcll(__ballot(m0.y == k));
            cnt[k - 1] += __popcll(__ballot(m0.z == k));
            cnt[k - 1] += __popcll(__ballot(m0.w == k));
            cnt[k - 1] += __popcll(__ballot(m1.x == k));
            cnt[k - 1] += __popcll(__ballot(m1.y == k));
            cnt[k - 1] += __popcll(__ballot(m1.z == k));
            cnt[k - 1] += __popcll(__ballot(m1.w == k));
        }
        if (lane == 0) {
            #pragma unroll
            for (int k = 0; k < 8; ++k) red_c[wave][k] = (float)cnt[k];
        }
    }

    const float* outbase = outputs + (size_t)b * NC * PIXELS + (size_t)chunk * CHUNK_PX;

    // ---- per-channel accumulation; NOT unrolled: keep registers minimal,
    //      let 32 resident waves/CU hide HBM latency (TLP over ILP) ----
    #pragma unroll 1
    for (int c = 0; c < NC; ++c) {
        const float4* o4 = (const float4*)(outbase + (size_t)c * PIXELS);
        float4 v0 = o4[t];
        float4 v1 = o4[t + BLOCK];

        float s[8];
        #pragma unroll
        for (int k = 0; k < 8; ++k) s[k] = 0.f;

        #pragma unroll
        for (int k = 1; k <= 8; ++k) {
            float a = s[k - 1];
            a += (m0.x == k) ? v0.x : 0.f;
            a += (m0.y == k) ? v0.y : 0.f;
            a += (m0.z == k) ? v0.z : 0.f;
            a += (m0.w == k) ? v0.w : 0.f;
            a += (m1.x == k) ? v1.x : 0.f;
            a += (m1.y == k) ? v1.y : 0.f;
            a += (m1.z == k) ? v1.z : 0.f;
            a += (m1.w == k) ? v1.w : 0.f;
            s[k - 1] = a;
        }

        float w = butterfly8(s, p, q, r);
        if (lane < 8) red[c][wave][(p << 2) | (q << 1) | r] = w;
    }

    __syncthreads();

    // ---- slot write: NO atomics, NO zero-init needed ----
    if (t < NC * 8) {                 // col = c*8 + k
        int c = t >> 3;
        int k = t & 7;
        float tot = 0.f;
        #pragma unroll
        for (int w = 0; w < NWAVE; ++w) tot += red[c][w][k];
        partial[(size_t)blk * SLOT + c * 8 + k] = tot;
    } else if (t < NC * 8 + 8) {      // col = 72 + k : class counts
        int k = t - NC * 8;
        float tot = 0.f;
        #pragma unroll
        for (int w = 0; w < NWAVE; ++w) tot += red_c[w][k];
        partial[(size_t)blk * SLOT + 72 + k] = tot;
    }
}

__global__ __launch_bounds__(1024)
void finalize_kernel(const float* __restrict__ partial,  // [GRID][SLOT]
                     float* __restrict__ out)
{
    __shared__ float tot[NB][SLOT];
    int t = threadIdx.x;

    // 640 threads: each reduces one (batch, col) over that batch's 288 blocks
    if (t < NB * SLOT) {
        int b = t / SLOT;
        int col = t % SLOT;
        const float* p = partial + (size_t)b * NCHUNK * SLOT + col;
        float s = 0.f;
        #pragma unroll 8
        for (int blk = 0; blk < NCHUNK; ++blk) s += p[(size_t)blk * SLOT];
        tot[b][col] = s;
    }
    __syncthreads();

    if (t < 64) {                    // one wave does the tiny math
        int b = t >> 3;
        int cls = t & 7;

        float cntv = tot[b][72 + cls];
        float denom = fmaxf(cntv, 1.0f);

        float pr[NC];
        float mx = -INFINITY;
        #pragma unroll
        for (int c = 0; c < NC; ++c) {
            pr[c] = tot[b][c * 8 + cls] / denom;
            mx = fmaxf(mx, pr[c]);
        }
        float se = 0.f;
        #pragma unroll
        for (int c = 0; c < NC; ++c) se += expf(pr[c] - mx);
        float lse = logf(se);

        float per = 0.f;
        #pragma unroll
        for (int c = 0; c < NC; ++c) {
            float tgt = (c == cls + 1) ? 0.9f : 0.0125f;
            per -= tgt * (pr[c] - mx - lse);
        }

        bool present = cntv > 0.f;
        float val = present ? per : 0.f;
        float np  = present ? 1.f : 0.f;
        #pragma unroll
        for (int off = 32; off > 0; off >>= 1) {
            val += __shfl_down(val, off, 64);
            np  += __shfl_down(np,  off, 64);
        }
        if (t == 0) out[0] = val / fmaxf(np, 1.f);
    }
}

extern "C" void kernel_launch(void* const* d_in, const int* in_sizes, int n_in,
                              void* d_out, int out_size, void* d_ws, size_t ws_size,
                              hipStream_t stream) {
    const int*   masks   = (const int*)d_in[0];
    const float* outputs = (const float*)d_in[1];
    float* partial = (float*)d_ws;   // GRID*SLOT floats = 720 KB, overwritten fully

    accum_kernel<<<GRID, BLOCK, 0, stream>>>(masks, outputs, partial);
    finalize_kernel<<<1, 1024, 0, stream>>>(partial, (float*)d_out);
}

// Round 3
// 238.744 us; speedup vs baseline: 1.1128x; 1.1128x over previous
//
#include <hip/hip_runtime.h>
#include <math.h>

// Problem constants (fixed by the reference)
#define NB 8
#define NC 9               // channels (== NUM_CLASSES)
#define PIXELS (768*768)   // 589824 pixels per batch image
#define BLOCK 256
#define PPT 8                          // pixels per thread (2 x int4)
#define CHUNK_PX (BLOCK * PPT)         // 2048
#define NCHUNK (PIXELS / CHUNK_PX)     // 288 exactly
#define NITER (PPT / 4)                // 2 vector iterations
#define NWAVE (BLOCK / 64)
#define GRID (NB * NCHUNK)             // 2304 blocks = 9 per CU
#define SLOT 80                        // per-block partial: 72 sums + 8 counts
#define ROWSPLIT 3                     // reduce stage: 3 row-groups per column

typedef float f32x4 __attribute__((ext_vector_type(4)));
typedef int   i32x4 __attribute__((ext_vector_type(4)));

// split-butterfly wave reduction: 8 class-sums partitioned across lanes.
// On return, lanes 0..7 hold the wave total for class cls = (p<<2)|(q<<1)|r.
__device__ __forceinline__ float butterfly8(const float s[8], int p, int q, int r)
{
    float u[4];
    #pragma unroll
    for (int j = 0; j < 4; ++j) {
        float x = p ? s[j] : s[j + 4];
        float y = __shfl_xor(x, 1, 64);
        u[j] = (p ? s[j + 4] : s[j]) + y;
    }
    float v2[2];
    #pragma unroll
    for (int j = 0; j < 2; ++j) {
        float x = q ? u[j] : u[j + 2];
        float y = __shfl_xor(x, 2, 64);
        v2[j] = (q ? u[j + 2] : u[j]) + y;
    }
    float w;
    {
        float x = r ? v2[0] : v2[1];
        float y = __shfl_xor(x, 4, 64);
        w = (r ? v2[1] : v2[0]) + y;
    }
    w += __shfl_xor(w, 8, 64);
    w += __shfl_xor(w, 16, 64);
    w += __shfl_xor(w, 32, 64);
    return w;
}

__global__ __launch_bounds__(BLOCK, 4)
void accum_kernel(const int* __restrict__ masks,
                  const float* __restrict__ outputs,
                  float* __restrict__ partial)   // [GRID][SLOT]
{
    int blk = blockIdx.x;
    int chunk = blk % NCHUNK;
    int b = blk / NCHUNK;
    int t = threadIdx.x;
    int wave = t >> 6;
    int lane = t & 63;

    // ---- load mask chunk ONCE (non-temporal: every byte read exactly once) ----
    const i32x4* __restrict__ m4 =
        (const i32x4*)(masks + (size_t)b * PIXELS + (size_t)chunk * CHUNK_PX);
    i32x4 m[NITER];
    #pragma unroll
    for (int i = 0; i < NITER; ++i) m[i] = __builtin_nontemporal_load(m4 + t + i * BLOCK);

    // ---- one-hot float masks, computed ONCE, reused by all 9 channels ----
    float fm[PPT][8];
    #pragma unroll
    for (int i = 0; i < NITER; ++i) {
        #pragma unroll
        for (int e = 0; e < 4; ++e) {
            int mv = m[i][e];
            #pragma unroll
            for (int k = 0; k < 8; ++k)
                fm[i * 4 + e][k] = (mv == k + 1) ? 1.0f : 0.0f;
        }
    }

    __shared__ float red[NC][NWAVE][8];   // per-channel per-wave class sums
    __shared__ float red_c[NWAVE][8];     // per-wave class counts

    const int p = lane & 1;
    const int q = (lane >> 1) & 1;
    const int r = (lane >> 2) & 1;

    // ---- counts: sum of one-hot masks (exact small ints in fp32) ----
    {
        float cnt[8];
        #pragma unroll
        for (int k = 0; k < 8; ++k) cnt[k] = 0.f;
        #pragma unroll
        for (int e = 0; e < PPT; ++e) {
            #pragma unroll
            for (int k = 0; k < 8; ++k) cnt[k] += fm[e][k];
        }
        float w = butterfly8(cnt, p, q, r);
        if (lane < 8) red_c[wave][(p << 2) | (q << 1) | r] = w;
    }

    const float* outbase = outputs + (size_t)b * NC * PIXELS + (size_t)chunk * CHUNK_PX;

    // ---- per-channel accumulation: 1 fmac per (elem, class) ----
    #pragma unroll
    for (int c = 0; c < NC; ++c) {
        const f32x4* o4 = (const f32x4*)(outbase + (size_t)c * PIXELS);
        f32x4 buf[NITER];
        #pragma unroll
        for (int i = 0; i < NITER; ++i) buf[i] = __builtin_nontemporal_load(o4 + t + i * BLOCK);

        float s[8];
        #pragma unroll
        for (int k = 0; k < 8; ++k) s[k] = 0.f;

        #pragma unroll
        for (int i = 0; i < NITER; ++i) {
            #pragma unroll
            for (int e = 0; e < 4; ++e) {
                float v = buf[i][e];
                #pragma unroll
                for (int k = 0; k < 8; ++k)
                    s[k] = fmaf(fm[i * 4 + e][k], v, s[k]);
            }
        }

        float w = butterfly8(s, p, q, r);
        if (lane < 8) red[c][wave][(p << 2) | (q << 1) | r] = w;
    }

    __syncthreads();

    // ---- slot write: NO atomics, NO zero-init needed ----
    if (t < NC * 8) {                 // col = c*8 + k
        int c = t >> 3;
        int k = t & 7;
        float tot = 0.f;
        #pragma unroll
        for (int w = 0; w < NWAVE; ++w) tot += red[c][w][k];
        partial[(size_t)blk * SLOT + c * 8 + k] = tot;
    } else if (t < NC * 8 + 8) {      // col = 72 + k : class counts
        int k = t - NC * 8;
        float tot = 0.f;
        #pragma unroll
        for (int w = 0; w < NWAVE; ++w) tot += red_c[w][k];
        partial[(size_t)blk * SLOT + 72 + k] = tot;
    }
}

// Stage 2: 8 blocks (one per batch), each reduces its 288 x 80 partial slab.
// 3-way row-split per column -> 240 latency streams per block, 8 CUs in parallel.
__global__ __launch_bounds__(256)
void reduce_kernel(const float* __restrict__ partial,  // [GRID][SLOT]
                   float* __restrict__ tot)            // [NB][SLOT]
{
    int b = blockIdx.x;
    int t = threadIdx.x;
    __shared__ float acc[ROWSPLIT][SLOT];

    if (t < SLOT * ROWSPLIT) {
        int col = t % SLOT;
        int rg  = t / SLOT;
        const float* p = partial + (size_t)b * NCHUNK * SLOT + col;
        float s = 0.f;
        #pragma unroll 8
        for (int row = rg; row < NCHUNK; row += ROWSPLIT)
            s += __builtin_nontemporal_load(p + (size_t)row * SLOT);
        acc[rg][col] = s;
    }
    __syncthreads();

    if (t < SLOT)
        tot[(size_t)b * SLOT + t] = acc[0][t] + acc[1][t] + acc[2][t];
}

// Stage 3: one wave does the tiny per-(b,cls) math and the final mean.
__global__ __launch_bounds__(64)
void final_kernel(const float* __restrict__ tot,  // [NB][SLOT]
                  float* __restrict__ out)
{
    int t = threadIdx.x;
    int b = t >> 3;
    int cls = t & 7;

    float cntv = tot[(size_t)b * SLOT + 72 + cls];
    float denom = fmaxf(cntv, 1.0f);

    float pr[NC];
    float mx = -INFINITY;
    #pragma unroll
    for (int c = 0; c < NC; ++c) {
        pr[c] = tot[(size_t)b * SLOT + c * 8 + cls] / denom;
        mx = fmaxf(mx, pr[c]);
    }
    float se = 0.f;
    #pragma unroll
    for (int c = 0; c < NC; ++c) se += expf(pr[c] - mx);
    float lse = logf(se);

    float per = 0.f;
    #pragma unroll
    for (int c = 0; c < NC; ++c) {
        float tgt = (c == cls + 1) ? 0.9f : 0.0125f;
        per -= tgt * (pr[c] - mx - lse);
    }

    bool present = cntv > 0.f;
    float val = present ? per : 0.f;
    float np  = present ? 1.f : 0.f;
    #pragma unroll
    for (int off = 32; off > 0; off >>= 1) {
        val += __shfl_down(val, off, 64);
        np  += __shfl_down(np,  off, 64);
    }
    if (t == 0) out[0] = val / fmaxf(np, 1.f);
}

extern "C" void kernel_launch(void* const* d_in, const int* in_sizes, int n_in,
                              void* d_out, int out_size, void* d_ws, size_t ws_size,
                              hipStream_t stream) {
    const int*   masks   = (const int*)d_in[0];
    const float* outputs = (const float*)d_in[1];
    float* partial = (float*)d_ws;                       // GRID*SLOT floats = 720 KB
    float* tot     = (float*)((char*)d_ws + 768 * 1024); // NB*SLOT floats = 2.5 KB

    accum_kernel<<<GRID, BLOCK, 0, stream>>>(masks, outputs, partial);
    reduce_kernel<<<NB, 256, 0, stream>>>(partial, tot);
    final_kernel<<<1, 64, 0, stream>>>(tot, (float*)d_out);
}

// Round 5
// 237.763 us; speedup vs baseline: 1.1174x; 1.0041x over previous
//
#include <hip/hip_runtime.h>
#include <math.h>

// Problem constants (fixed by the reference)
#define NB 8
#define NC 9               // channels (== NUM_CLASSES)
#define PIXELS (768*768)   // 589824 pixels per batch image
#define BLOCK 256
#define PPT 8                          // pixels per thread (2 x int4)
#define CHUNK_PX (BLOCK * PPT)         // 2048
#define NCHUNK (PIXELS / CHUNK_PX)     // 288 exactly
#define NITER (PPT / 4)                // 2 vector iterations
#define NWAVE (BLOCK / 64)
#define GRID (NB * NCHUNK)             // 2304 blocks = 9 per CU
#define SLOT 80                        // per-block partial: 72 sums + 8 counts
#define ROWSPLIT 3                     // reduce stage: 3 row-groups per column

typedef float f32x4 __attribute__((ext_vector_type(4)));
typedef int   i32x4 __attribute__((ext_vector_type(4)));

// split-butterfly wave reduction: 8 class-sums partitioned across lanes.
// On return, lanes 0..7 hold the wave total for class cls = (p<<2)|(q<<1)|r.
__device__ __forceinline__ float butterfly8(const float s[8], int p, int q, int r)
{
    float u[4];
    #pragma unroll
    for (int j = 0; j < 4; ++j) {
        float x = p ? s[j] : s[j + 4];
        float y = __shfl_xor(x, 1, 64);
        u[j] = (p ? s[j + 4] : s[j]) + y;
    }
    float v2[2];
    #pragma unroll
    for (int j = 0; j < 2; ++j) {
        float x = q ? u[j] : u[j + 2];
        float y = __shfl_xor(x, 2, 64);
        v2[j] = (q ? u[j + 2] : u[j]) + y;
    }
    float w;
    {
        float x = r ? v2[0] : v2[1];
        float y = __shfl_xor(x, 4, 64);
        w = (r ? v2[1] : v2[0]) + y;
    }
    w += __shfl_xor(w, 8, 64);
    w += __shfl_xor(w, 16, 64);
    w += __shfl_xor(w, 32, 64);
    return w;
}

__global__ __launch_bounds__(BLOCK, 4)
void accum_kernel(const int* __restrict__ masks,
                  const float* __restrict__ outputs,
                  float* __restrict__ partial,   // [GRID][SLOT]
                  unsigned int* __restrict__ counter)
{
    int blk = blockIdx.x;
    int chunk = blk % NCHUNK;
    int b = blk / NCHUNK;
    int t = threadIdx.x;
    int wave = t >> 6;
    int lane = t & 63;

    // ---- load mask chunk ONCE (non-temporal: every byte read exactly once) ----
    const i32x4* __restrict__ m4 =
        (const i32x4*)(masks + (size_t)b * PIXELS + (size_t)chunk * CHUNK_PX);
    i32x4 m[NITER];
    #pragma unroll
    for (int i = 0; i < NITER; ++i) m[i] = __builtin_nontemporal_load(m4 + t + i * BLOCK);

    // reset the arrival counter for the next stage; stream-ordering guarantees
    // all reduce_final increments happen after this kernel fully completes,
    // and this reset happens after the PREVIOUS reduce_final completed.
    if (blk == 0 && t == 0)
        __hip_atomic_store(counter, 0u, __ATOMIC_RELAXED, __HIP_MEMORY_SCOPE_AGENT);

    // ---- one-hot float masks, computed ONCE, reused by all 9 channels ----
    float fm[PPT][8];
    #pragma unroll
    for (int i = 0; i < NITER; ++i) {
        #pragma unroll
        for (int e = 0; e < 4; ++e) {
            int mv = m[i][e];
            #pragma unroll
            for (int k = 0; k < 8; ++k)
                fm[i * 4 + e][k] = (mv == k + 1) ? 1.0f : 0.0f;
        }
    }

    __shared__ float red[NC][NWAVE][8];   // per-channel per-wave class sums
    __shared__ float red_c[NWAVE][8];     // per-wave class counts

    const int p = lane & 1;
    const int q = (lane >> 1) & 1;
    const int r = (lane >> 2) & 1;

    // ---- counts: sum of one-hot masks (exact small ints in fp32) ----
    {
        float cnt[8];
        #pragma unroll
        for (int k = 0; k < 8; ++k) cnt[k] = 0.f;
        #pragma unroll
        for (int e = 0; e < PPT; ++e) {
            #pragma unroll
            for (int k = 0; k < 8; ++k) cnt[k] += fm[e][k];
        }
        float w = butterfly8(cnt, p, q, r);
        if (lane < 8) red_c[wave][(p << 2) | (q << 1) | r] = w;
    }

    const float* outbase = outputs + (size_t)b * NC * PIXELS + (size_t)chunk * CHUNK_PX;

    // ---- per-channel accumulation: 1 fmac per (elem, class) ----
    #pragma unroll
    for (int c = 0; c < NC; ++c) {
        const f32x4* o4 = (const f32x4*)(outbase + (size_t)c * PIXELS);
        f32x4 buf[NITER];
        #pragma unroll
        for (int i = 0; i < NITER; ++i) buf[i] = __builtin_nontemporal_load(o4 + t + i * BLOCK);

        float s[8];
        #pragma unroll
        for (int k = 0; k < 8; ++k) s[k] = 0.f;

        #pragma unroll
        for (int i = 0; i < NITER; ++i) {
            #pragma unroll
            for (int e = 0; e < 4; ++e) {
                float v = buf[i][e];
                #pragma unroll
                for (int k = 0; k < 8; ++k)
                    s[k] = fmaf(fm[i * 4 + e][k], v, s[k]);
            }
        }

        float w = butterfly8(s, p, q, r);
        if (lane < 8) red[c][wave][(p << 2) | (q << 1) | r] = w;
    }

    __syncthreads();

    // ---- slot write: NO atomics, NO zero-init needed ----
    if (t < NC * 8) {                 // col = c*8 + k
        int c = t >> 3;
        int k = t & 7;
        float tot = 0.f;
        #pragma unroll
        for (int w = 0; w < NWAVE; ++w) tot += red[c][w][k];
        partial[(size_t)blk * SLOT + c * 8 + k] = tot;
    } else if (t < NC * 8 + 8) {      // col = 72 + k : class counts
        int k = t - NC * 8;
        float tot = 0.f;
        #pragma unroll
        for (int w = 0; w < NWAVE; ++w) tot += red_c[w][k];
        partial[(size_t)blk * SLOT + 72 + k] = tot;
    }
}

// Stage 2+3 fused: 8 blocks (one per batch) reduce their 288 x 80 slab; the
// LAST block to finish (agent-scope arrival counter) also does the final math.
// No spin-wait anywhere: deadlock-free regardless of scheduling order.
// Final arithmetic is identical (same order) to the 3-kernel round-3 version.
__global__ __launch_bounds__(256)
void reduce_final_kernel(const float* __restrict__ partial,  // [GRID][SLOT]
                         float* __restrict__ tot,            // [NB][SLOT]
                         unsigned int* __restrict__ counter,
                         float* __restrict__ out)
{
    int b = blockIdx.x;
    int t = threadIdx.x;
    __shared__ float acc[ROWSPLIT][SLOT];
    __shared__ int islast;

    if (t < SLOT * ROWSPLIT) {
        int col = t % SLOT;
        int rg  = t / SLOT;
        const float* p = partial + (size_t)b * NCHUNK * SLOT + col;
        float s = 0.f;
        #pragma unroll 8
        for (int row = rg; row < NCHUNK; row += ROWSPLIT)
            s += __builtin_nontemporal_load(p + (size_t)row * SLOT);
        acc[rg][col] = s;
    }
    __syncthreads();

    if (t < SLOT) {
        // agent-scope store: device-visible (cross-XCD) for the last block
        __hip_atomic_store(&tot[(size_t)b * SLOT + t],
                           acc[0][t] + acc[1][t] + acc[2][t],
                           __ATOMIC_RELAXED, __HIP_MEMORY_SCOPE_AGENT);
    }
    __syncthreads();

    if (t == 0) {
        unsigned int old = __hip_atomic_fetch_add(counter, 1u,
                                                  __ATOMIC_ACQ_REL,
                                                  __HIP_MEMORY_SCOPE_AGENT);
        islast = (old == NB - 1) ? 1 : 0;
    }
    __syncthreads();

    if (islast && t < 64) {          // one wave does the tiny math
        int bb = t >> 3;
        int cls = t & 7;

        float cntv = __hip_atomic_load(&tot[(size_t)bb * SLOT + 72 + cls],
                                       __ATOMIC_RELAXED, __HIP_MEMORY_SCOPE_AGENT);
        float denom = fmaxf(cntv, 1.0f);

        float pr[NC];
        float mx = -INFINITY;
        #pragma unroll
        for (int c = 0; c < NC; ++c) {
            float sv = __hip_atomic_load(&tot[(size_t)bb * SLOT + c * 8 + cls],
                                         __ATOMIC_RELAXED, __HIP_MEMORY_SCOPE_AGENT);
            pr[c] = sv / denom;
            mx = fmaxf(mx, pr[c]);
        }
        float se = 0.f;
        #pragma unroll
        for (int c = 0; c < NC; ++c) se += expf(pr[c] - mx);
        float lse = logf(se);

        float per = 0.f;
        #pragma unroll
        for (int c = 0; c < NC; ++c) {
            float tgt = (c == cls + 1) ? 0.9f : 0.0125f;
            per -= tgt * (pr[c] - mx - lse);
        }

        bool present = cntv > 0.f;
        float val = present ? per : 0.f;
        float np  = present ? 1.f : 0.f;
        #pragma unroll
        for (int off = 32; off > 0; off >>= 1) {
            val += __shfl_down(val, off, 64);
            np  += __shfl_down(np,  off, 64);
        }
        if (t == 0) out[0] = val / fmaxf(np, 1.f);
    }
}

extern "C" void kernel_launch(void* const* d_in, const int* in_sizes, int n_in,
                              void* d_out, int out_size, void* d_ws, size_t ws_size,
                              hipStream_t stream) {
    const int*   masks   = (const int*)d_in[0];
    const float* outputs = (const float*)d_in[1];
    float* partial = (float*)d_ws;                            // 720 KB
    float* tot     = (float*)((char*)d_ws + 768 * 1024);      // 2.5 KB
    unsigned int* counter = (unsigned int*)((char*)d_ws + 772 * 1024);

    accum_kernel<<<GRID, BLOCK, 0, stream>>>(masks, outputs, partial, counter);
    reduce_final_kernel<<<NB, 256, 0, stream>>>(partial, tot, counter, (float*)d_out);
}